// Round 2
// baseline (805.104 us; speedup 1.0000x reference)
//
#include <hip/hip_runtime.h>

typedef unsigned short u16;
typedef unsigned int   u32;
using bf16x8 = __attribute__((ext_vector_type(8))) __bf16;
using f32x4  = __attribute__((ext_vector_type(4))) float;

#define B_    4
#define SQ_   2048
#define SKV_  2048
#define E_    1024
#define H_    16
#define NHD_  1024   // H * 64

__device__ __forceinline__ u16 f2bf(float f) {
  u32 u = __float_as_uint(f);
  u32 r = u + 0x7FFFu + ((u >> 16) & 1u);   // RNE
  return (u16)(r >> 16);
}

__device__ __forceinline__ void gload_lds16(const void* g, void* l) {
  __builtin_amdgcn_global_load_lds((const __attribute__((address_space(1))) u32*)g,
                                   (__attribute__((address_space(3))) u32*)l,
                                   16, 0, 0);
}

// ---------------- fp32 -> bf16 elementwise ----------------
__global__ __launch_bounds__(256) void cvt_bf16_kernel(const float* __restrict__ src,
                                                       u16* __restrict__ dst, int n4) {
  int i = blockIdx.x * 256 + threadIdx.x;
  int stride = gridDim.x * 256;
  for (; i < n4; i += stride) {
    float4 v = reinterpret_cast<const float4*>(src)[i];
    u32 lo = (u32)f2bf(v.x) | ((u32)f2bf(v.y) << 16);
    u32 hi = (u32)f2bf(v.z) | ((u32)f2bf(v.w) << 16);
    reinterpret_cast<uint2*>(dst)[i] = make_uint2(lo, hi);
  }
}

// ---------------- weight transpose + convert: wT[n][k] ----------------
__global__ __launch_bounds__(256) void wtrans_kernel(const float* __restrict__ w0,
                                                     const float* __restrict__ w1,
                                                     const float* __restrict__ w2,
                                                     u16* __restrict__ wt) {
  const float* w = (blockIdx.z == 0) ? w0 : (blockIdx.z == 1) ? w1 : w2;
  u16* dst = wt + (size_t)blockIdx.z * (E_ * NHD_);
  __shared__ float t[32][33];
  int tx = threadIdx.x & 31, ty = threadIdx.x >> 5;   // ty 0..7
  int k0 = blockIdx.x * 32, n0 = blockIdx.y * 32;
  for (int i = 0; i < 4; ++i)
    t[ty + i * 8][tx] = w[(size_t)(k0 + ty + i * 8) * NHD_ + n0 + tx];
  __syncthreads();
  for (int i = 0; i < 4; ++i)
    dst[(size_t)(n0 + ty + i * 8) * E_ + k0 + tx] = f2bf(t[tx][ty + i * 8]);
}

// ---------------- fused QKV projection GEMM (bf16 MFMA) ----------------
// z = 0: Q[b][h][s][d]   z = 1: K[b][h][s][d]   z = 2: Vt[b][h][d][s]
__global__ __launch_bounds__(256) void proj_kernel(
    const u16* __restrict__ xq, const u16* __restrict__ xkv,
    const u16* __restrict__ wt,
    const float* __restrict__ bq, const float* __restrict__ bk, const float* __restrict__ bv,
    u16* __restrict__ Qo, u16* __restrict__ Ko, u16* __restrict__ Vto)
{
  const int pz = blockIdx.z;
  const u16* X = (pz == 0) ? xq : xkv;
  const u16* W = wt + (size_t)pz * (E_ * NHD_);
  const float* bias = (pz == 0) ? bq : (pz == 1) ? bk : bv;

  __shared__ alignas(16) u16 As[128 * 64];
  __shared__ alignas(16) u16 Bs[128 * 64];

  const int tid = threadIdx.x;
  const int lane = tid & 63, wv = tid >> 6;
  const int wm = wv >> 1, wn = wv & 1;
  const int m0 = blockIdx.x * 128, n0 = blockIdx.y * 128;
  const int l15 = lane & 15, lhi = lane >> 4;
  const int srow = lane >> 3;          // 0..7
  const int scol = (lane & 7) * 8;     // 0,8,..,56

  f32x4 acc[4][4] = {};

  for (int k0 = 0; k0 < E_; k0 += 64) {
    for (int i = 0; i < 4; ++i) {
      int chunk = wv * 4 + i;          // 16 chunks of 8 rows x 64 k
      gload_lds16(X + (size_t)(m0 + chunk * 8 + srow) * E_ + k0 + scol, As + chunk * 512);
      gload_lds16(W + (size_t)(n0 + chunk * 8 + srow) * E_ + k0 + scol, Bs + chunk * 512);
    }
    __syncthreads();
    for (int kk = 0; kk < 2; ++kk) {
      bf16x8 af[4], bfg[4];
      for (int i = 0; i < 4; ++i)
        af[i] = *reinterpret_cast<const bf16x8*>(As + (wm * 64 + i * 16 + l15) * 64 + kk * 32 + lhi * 8);
      for (int j = 0; j < 4; ++j)
        bfg[j] = *reinterpret_cast<const bf16x8*>(Bs + (wn * 64 + j * 16 + l15) * 64 + kk * 32 + lhi * 8);
      for (int i = 0; i < 4; ++i)
        for (int j = 0; j < 4; ++j)
          acc[i][j] = __builtin_amdgcn_mfma_f32_16x16x32_bf16(af[i], bfg[j], acc[i][j], 0, 0, 0);
    }
    __syncthreads();
  }

  for (int i = 0; i < 4; ++i) {
    for (int j = 0; j < 4; ++j) {
      int n = n0 + wn * 64 + j * 16 + l15;
      float bb = bias[n];
      int h = n >> 6, d = n & 63;
      for (int r = 0; r < 4; ++r) {
        int m = m0 + wm * 64 + i * 16 + lhi * 4 + r;   // C row = (lane>>4)*4 + r  [m89]
        int b = m >> 11, s = m & 2047;
        u16 o = f2bf(acc[i][j][r] + bb);
        if (pz == 0)
          Qo[(((size_t)(b * H_ + h) * SQ_ + s) << 6) + d] = o;
        else if (pz == 1)
          Ko[(((size_t)(b * H_ + h) * SKV_ + s) << 6) + d] = o;
        else
          Vto[(((size_t)(b * H_ + h) * 64 + d) << 11) + s] = o;
      }
    }
  }
}

// ---------------- flash attention (4 waves, 16 q-rows/wave, KV chunks of 32) ----------------
__global__ __launch_bounds__(256) void attn_kernel(
    const u16* __restrict__ Q, const u16* __restrict__ K, const u16* __restrict__ Vt,
    const unsigned char* __restrict__ mask, float* __restrict__ out)
{
  __shared__ alignas(16) u16 pl[4 * 16 * 40];   // per-wave P tile [16][40] (pad vs bank conflicts)
  __shared__ int modeflag;

  const int tid = threadIdx.x;
  // --- runtime probe: is the bool mask stored as 1 byte or as int32? ---
  if (tid == 0) modeflag = 0;
  __syncthreads();
  {
    uint4 v = reinterpret_cast<const uint4*>(mask)[tid];          // first 4 KB
    u32 o = (v.x | v.y | v.z | v.w) & 0xFFFFFF00u;                // int32-encoded 0/1 => upper bytes all 0
    if (o) atomicOr(&modeflag, 1);
  }
  __syncthreads();
  const bool bytemode = (modeflag != 0);

  const int bh = blockIdx.y;
  const int b = bh >> 4;
  const int wv = tid >> 6, lane = tid & 63;
  const int l15 = lane & 15, lhi = lane >> 4;
  const int qb = blockIdx.x * 64 + wv * 16;

  const u16* Qp = Q + ((size_t)bh * SQ_ + qb) * 64;
  const u16* Kp = K + (size_t)bh * SKV_ * 64;
  const u16* Vp = Vt + (size_t)bh * 64 * SKV_;
  const unsigned char* Mb = mask + (size_t)b * SQ_ * SKV_;
  const int* Mi = reinterpret_cast<const int*>(mask) + (size_t)b * SQ_ * SKV_;

  bf16x8 qf0 = *reinterpret_cast<const bf16x8*>(Qp + l15 * 64 + lhi * 8);
  bf16x8 qf1 = *reinterpret_cast<const bf16x8*>(Qp + l15 * 64 + 32 + lhi * 8);

  f32x4 acc[4] = {};
  float mrow[4] = {-1e30f, -1e30f, -1e30f, -1e30f};
  float lrow[4] = {0.f, 0.f, 0.f, 0.f};

  u16* plw = pl + wv * (16 * 40);

  for (int kv0 = 0; kv0 < SKV_; kv0 += 32) {
    const u16* kb = Kp + (size_t)kv0 * 64;
    bf16x8 k00 = *reinterpret_cast<const bf16x8*>(kb + l15 * 64 + lhi * 8);
    bf16x8 k01 = *reinterpret_cast<const bf16x8*>(kb + l15 * 64 + 32 + lhi * 8);
    bf16x8 k10 = *reinterpret_cast<const bf16x8*>(kb + (16 + l15) * 64 + lhi * 8);
    bf16x8 k11 = *reinterpret_cast<const bf16x8*>(kb + (16 + l15) * 64 + 32 + lhi * 8);

    f32x4 s0 = {}, s1 = {};
    s0 = __builtin_amdgcn_mfma_f32_16x16x32_bf16(qf0, k00, s0, 0, 0, 0);
    s0 = __builtin_amdgcn_mfma_f32_16x16x32_bf16(qf1, k01, s0, 0, 0, 0);
    s1 = __builtin_amdgcn_mfma_f32_16x16x32_bf16(qf0, k10, s1, 0, 0, 0);
    s1 = __builtin_amdgcn_mfma_f32_16x16x32_bf16(qf1, k11, s1, 0, 0, 0);

    for (int r = 0; r < 4; ++r) {
      size_t ro = (size_t)(qb + lhi * 4 + r) * SKV_ + kv0;
      bool mb0, mb1;
      if (bytemode) { mb0 = Mb[ro + l15] != 0; mb1 = Mb[ro + 16 + l15] != 0; }
      else          { mb0 = Mi[ro + l15] != 0; mb1 = Mi[ro + 16 + l15] != 0; }
      float v0 = mb0 ? -1e30f : s0[r] * 0.125f;
      float v1 = mb1 ? -1e30f : s1[r] * 0.125f;
      float cm = fmaxf(v0, v1);
      cm = fmaxf(cm, __shfl_xor(cm, 1));
      cm = fmaxf(cm, __shfl_xor(cm, 2));
      cm = fmaxf(cm, __shfl_xor(cm, 4));
      cm = fmaxf(cm, __shfl_xor(cm, 8));
      float mnew = fmaxf(mrow[r], cm);
      float sc = __expf(mrow[r] - mnew);
      mrow[r] = mnew;
      float e0 = mb0 ? 0.f : __expf(v0 - mnew);   // masked => exactly 0 (matches exp(-1e9-max)==0)
      float e1 = mb1 ? 0.f : __expf(v1 - mnew);
      float rs = e0 + e1;
      rs += __shfl_xor(rs, 1);
      rs += __shfl_xor(rs, 2);
      rs += __shfl_xor(rs, 4);
      rs += __shfl_xor(rs, 8);
      lrow[r] = lrow[r] * sc + rs;
      acc[0][r] *= sc; acc[1][r] *= sc; acc[2][r] *= sc; acc[3][r] *= sc;
      plw[(lhi * 4 + r) * 40 + l15] = f2bf(e0);
      plw[(lhi * 4 + r) * 40 + 16 + l15] = f2bf(e1);
    }
    asm volatile("s_waitcnt lgkmcnt(0)" ::: "memory");   // P writes visible before A-frag reads
    bf16x8 pa = *reinterpret_cast<const bf16x8*>(plw + l15 * 40 + lhi * 8);
    const u16* vb = Vp + kv0 + lhi * 8;
    for (int n = 0; n < 4; ++n) {
      bf16x8 vf = *reinterpret_cast<const bf16x8*>(vb + (size_t)(n * 16 + l15) * SKV_);
      acc[n] = __builtin_amdgcn_mfma_f32_16x16x32_bf16(pa, vf, acc[n], 0, 0, 0);
    }
  }

  float* ob = out + ((size_t)b * SQ_ + qb) * NHD_ + (bh & 15) * 64;
  for (int r = 0; r < 4; ++r) {
    float inv = 1.0f / lrow[r];
    for (int n = 0; n < 4; ++n)
      ob[(size_t)(lhi * 4 + r) * NHD_ + n * 16 + l15] = acc[n][r] * inv;
  }
}

extern "C" void kernel_launch(void* const* d_in, const int* in_sizes, int n_in,
                              void* d_out, int out_size, void* d_ws, size_t ws_size,
                              hipStream_t stream) {
  const float* x_q  = (const float*)d_in[0];
  const float* x_kv = (const float*)d_in[1];
  const unsigned char* mask = (const unsigned char*)d_in[2];
  const float* w_q = (const float*)d_in[3];
  const float* b_q = (const float*)d_in[4];
  const float* w_k = (const float*)d_in[5];
  const float* b_k = (const float*)d_in[6];
  const float* w_v = (const float*)d_in[7];
  const float* b_v = (const float*)d_in[8];
  float* out = (float*)d_out;

  const size_t MB = 1024 * 1024;
  char* ws = (char*)d_ws;
  u16* xq_b  = (u16*)(ws);             // 16 MB
  u16* xkv_b = (u16*)(ws + 16 * MB);   // 16 MB
  u16* wt    = (u16*)(ws + 32 * MB);   //  6 MB (3 x 1024x1024 bf16)
  u16* Qb    = (u16*)(ws + 38 * MB);   // 16 MB
  u16* Kb    = (u16*)(ws + 54 * MB);   // 16 MB
  u16* Vtb   = (u16*)(ws + 70 * MB);   // 16 MB  -> total 86 MB
  if (ws_size < 86 * MB) return;       // fail loudly (poison stays) rather than corrupt

  cvt_bf16_kernel<<<2048, 256, 0, stream>>>(x_q,  xq_b,  (B_ * SQ_  * E_) / 4);
  cvt_bf16_kernel<<<2048, 256, 0, stream>>>(x_kv, xkv_b, (B_ * SKV_ * E_) / 4);
  wtrans_kernel<<<dim3(32, 32, 3), 256, 0, stream>>>(w_q, w_k, w_v, wt);
  proj_kernel<<<dim3(64, 8, 3), 256, 0, stream>>>(xq_b, xkv_b, wt, b_q, b_k, b_v, Qb, Kb, Vtb);
  attn_kernel<<<dim3(32, 64), 256, 0, stream>>>(Qb, Kb, Vtb, mask, out);
}

// Round 6
// 534.107 us; speedup vs baseline: 1.5074x; 1.5074x over previous
//
#include <hip/hip_runtime.h>

typedef unsigned short u16;
typedef unsigned int   u32;
using bf16x8 = __attribute__((ext_vector_type(8))) __bf16;
using f32x4  = __attribute__((ext_vector_type(4))) float;
using f32x16 = __attribute__((ext_vector_type(16))) float;

#define B_    4
#define SQ_   2048
#define SKV_  2048
#define E_    1024
#define H_    16
#define NHD_  1024
#define MWORDS 64   // SKV/32 packed mask words per row

__device__ __forceinline__ u16 f2bf(float f) {
  u32 u = __float_as_uint(f);
  u32 r = u + 0x7FFFu + ((u >> 16) & 1u);   // RNE
  return (u16)(r >> 16);
}

__device__ __forceinline__ void gload_lds16(const void* g, void* l) {
  __builtin_amdgcn_global_load_lds((const __attribute__((address_space(1))) u32*)g,
                                   (__attribute__((address_space(3))) u32*)l,
                                   16, 0, 0);
}

// ---------------- fp32 -> bf16 elementwise ----------------
__global__ __launch_bounds__(256) void cvt_bf16_kernel(const float* __restrict__ src,
                                                       u16* __restrict__ dst, int n4) {
  int i = blockIdx.x * 256 + threadIdx.x;
  int stride = gridDim.x * 256;
  for (; i < n4; i += stride) {
    float4 v = reinterpret_cast<const float4*>(src)[i];
    u32 lo = (u32)f2bf(v.x) | ((u32)f2bf(v.y) << 16);
    u32 hi = (u32)f2bf(v.z) | ((u32)f2bf(v.w) << 16);
    reinterpret_cast<uint2*>(dst)[i] = make_uint2(lo, hi);
  }
}

// ---------------- weight transpose + convert: wT[n][k] ----------------
__global__ __launch_bounds__(256) void wtrans_kernel(const float* __restrict__ w0,
                                                     const float* __restrict__ w1,
                                                     const float* __restrict__ w2,
                                                     u16* __restrict__ wt) {
  const float* w = (blockIdx.z == 0) ? w0 : (blockIdx.z == 1) ? w1 : w2;
  u16* dst = wt + (size_t)blockIdx.z * (E_ * NHD_);
  __shared__ float t[32][33];
  int tx = threadIdx.x & 31, ty = threadIdx.x >> 5;
  int k0 = blockIdx.x * 32, n0 = blockIdx.y * 32;
  for (int i = 0; i < 4; ++i)
    t[ty + i * 8][tx] = w[(size_t)(k0 + ty + i * 8) * NHD_ + n0 + tx];
  __syncthreads();
  for (int i = 0; i < 4; ++i)
    dst[(size_t)(n0 + ty + i * 8) * E_ + k0 + tx] = f2bf(t[tx][ty + i * 8]);
}

// ---------------- fused QKV projection GEMM (bf16 MFMA) ----------------
// z=0: Q[b][h][s][d] (pre-scaled by 1/8)  z=1: K[b][h][s][d]  z=2: Vt[b][h][d][s]
__global__ __launch_bounds__(256) void proj_kernel(
    const u16* __restrict__ xq, const u16* __restrict__ xkv,
    const u16* __restrict__ wt,
    const float* __restrict__ bq, const float* __restrict__ bk, const float* __restrict__ bv,
    u16* __restrict__ Qo, u16* __restrict__ Ko, u16* __restrict__ Vto)
{
  const int pz = blockIdx.z;
  const u16* X = (pz == 0) ? xq : xkv;
  const u16* W = wt + (size_t)pz * (E_ * NHD_);
  const float* bias = (pz == 0) ? bq : (pz == 1) ? bk : bv;
  const float scale = (pz == 0) ? 0.125f : 1.0f;   // fold 1/sqrt(DK) into Q

  __shared__ alignas(16) u16 As[128 * 64];
  __shared__ alignas(16) u16 Bs[128 * 64];

  const int tid = threadIdx.x;
  const int lane = tid & 63, wv = tid >> 6;
  const int wm = wv >> 1, wn = wv & 1;
  const int m0 = blockIdx.x * 128, n0 = blockIdx.y * 128;
  const int l15 = lane & 15, lhi = lane >> 4;
  const int srow = lane >> 3;
  const int scol = (lane & 7) * 8;

  f32x4 acc[4][4] = {};

  for (int k0 = 0; k0 < E_; k0 += 64) {
    for (int i = 0; i < 4; ++i) {
      int chunk = wv * 4 + i;
      gload_lds16(X + (size_t)(m0 + chunk * 8 + srow) * E_ + k0 + scol, As + chunk * 512);
      gload_lds16(W + (size_t)(n0 + chunk * 8 + srow) * E_ + k0 + scol, Bs + chunk * 512);
    }
    __syncthreads();
    for (int kk = 0; kk < 2; ++kk) {
      bf16x8 af[4], bfg[4];
      for (int i = 0; i < 4; ++i)
        af[i] = *reinterpret_cast<const bf16x8*>(As + (wm * 64 + i * 16 + l15) * 64 + kk * 32 + lhi * 8);
      for (int j = 0; j < 4; ++j)
        bfg[j] = *reinterpret_cast<const bf16x8*>(Bs + (wn * 64 + j * 16 + l15) * 64 + kk * 32 + lhi * 8);
      for (int i = 0; i < 4; ++i)
        for (int j = 0; j < 4; ++j)
          acc[i][j] = __builtin_amdgcn_mfma_f32_16x16x32_bf16(af[i], bfg[j], acc[i][j], 0, 0, 0);
    }
    __syncthreads();
  }

  for (int i = 0; i < 4; ++i) {
    for (int j = 0; j < 4; ++j) {
      int n = n0 + wn * 64 + j * 16 + l15;
      float bb = bias[n];
      int h = n >> 6, d = n & 63;
      for (int r = 0; r < 4; ++r) {
        int m = m0 + wm * 64 + i * 16 + lhi * 4 + r;
        int b = m >> 11, s = m & 2047;
        u16 o = f2bf((acc[i][j][r] + bb) * scale);
        if (pz == 0)
          Qo[(((size_t)(b * H_ + h) * SQ_ + s) << 6) + d] = o;
        else if (pz == 1)
          Ko[(((size_t)(b * H_ + h) * SKV_ + s) << 6) + d] = o;
        else
          Vto[(((size_t)(b * H_ + h) * 64 + d) << 11) + s] = o;
      }
    }
  }
}

// ---------------- mask width probe + bit-pack ----------------
__global__ void probe_kernel(const u32* __restrict__ mask, u32* __restrict__ flag) {
  int tid = threadIdx.x;
  if (tid == 0) *flag = 0;
  __syncthreads();
  uint4 v = reinterpret_cast<const uint4*>(mask)[tid];   // first 4 KB
  if ((v.x | v.y | v.z | v.w) & 0xFFFFFF00u) atomicOr(flag, 1u);  // nonzero high bytes => byte mask
}

__global__ __launch_bounds__(256) void maskpack_kernel(const u32* __restrict__ mask,
                                                       const u32* __restrict__ flag,
                                                       u32* __restrict__ Mp) {
  __shared__ u32 fsh;
  if (threadIdx.x == 0) fsh = *flag;
  __syncthreads();
  const bool bytemode = (fsh != 0);
  int wid = blockIdx.x * 256 + threadIdx.x;   // one 32-bit mask word per thread
  u32 word = 0;
  if (bytemode) {
    uint4 a = reinterpret_cast<const uint4*>(mask)[(size_t)wid * 2];
    uint4 b = reinterpret_cast<const uint4*>(mask)[(size_t)wid * 2 + 1];
    u32 u[8] = {a.x, a.y, a.z, a.w, b.x, b.y, b.z, b.w};
#pragma unroll
    for (int k = 0; k < 8; ++k) {
      u32 nib = (((u[k] & 0x01010101u) * 0x01020408u) >> 24) & 0xFu;  // 4 bool bytes -> nibble
      word |= nib << (4 * k);
    }
  } else {
    const uint4* mi = reinterpret_cast<const uint4*>(mask) + (size_t)wid * 8;
#pragma unroll
    for (int k = 0; k < 8; ++k) {
      uint4 q4 = mi[k];
      u32 nib = (q4.x & 1u) | ((q4.y & 1u) << 1) | ((q4.z & 1u) << 2) | ((q4.w & 1u) << 3);
      word |= nib << (4 * k);
    }
  }
  Mp[wid] = word;
}

// ---------------- flash attention: swapped QK^T, 32x32 MFMA, register softmax ----------------
// Wave owns 32 q-rows. S^T = mfma(K,Q): lane holds q-col (lane&31), 16 kv rows in regs.
// P->bf16 via f2bf pack; lane-pair (c <-> 32+c) redistribution via shfl_xor(32) + select.
__global__ __launch_bounds__(256) void attn_kernel(
    const u16* __restrict__ Q, const u16* __restrict__ K, const u16* __restrict__ Vt,
    const u32* __restrict__ Mp, float* __restrict__ out)
{
  const int o = blockIdx.x;                     // 1024 blocks
  const int bh   = (o & 7) * 8 + (o >> 7);      // XCD swizzle: same-bh blocks share an XCD
  const int qblk = (o >> 3) & 15;
  const int b = bh >> 4, h = bh & 15;
  const int lane = threadIdx.x & 63, wv = threadIdx.x >> 6;
  const int l31 = lane & 31, hi = lane >> 5;
  const int qg = qblk * 128 + wv * 32 + l31;

  const u16* Qp = Q + ((size_t)bh * SQ_ + qblk * 128 + wv * 32) * 64;
  const u16* Kp = K + (size_t)bh * SKV_ * 64;
  const u16* Vp = Vt + (size_t)bh * 64 * SKV_;
  const u32* Mrow = Mp + ((size_t)b * SQ_ + qg) * MWORDS;

  bf16x8 qf[4];
#pragma unroll
  for (int t = 0; t < 4; ++t)
    qf[t] = *reinterpret_cast<const bf16x8*>(Qp + (size_t)l31 * 64 + t * 16 + hi * 8);

  f32x16 acc0 = {}, acc1 = {};
  float mreg = -1.0e4f, lr = 0.f;   // floor at -1e4: masked rows give exact p=0, no bogus state

  typedef union { u32 w[4]; bf16x8 f; } fragu;

  for (int kv0 = 0; kv0 < SKV_; kv0 += 32) {
    const u16* kb = Kp + (size_t)kv0 * 64;
    bf16x8 kf0 = *reinterpret_cast<const bf16x8*>(kb + (size_t)l31 * 64 + 0  + hi * 8);
    bf16x8 kf1 = *reinterpret_cast<const bf16x8*>(kb + (size_t)l31 * 64 + 16 + hi * 8);
    bf16x8 kf2 = *reinterpret_cast<const bf16x8*>(kb + (size_t)l31 * 64 + 32 + hi * 8);
    bf16x8 kf3 = *reinterpret_cast<const bf16x8*>(kb + (size_t)l31 * 64 + 48 + hi * 8);
    u32 mw = Mrow[kv0 >> 5];
    const u16* vb = Vp + kv0;
    bf16x8 vf00 = *reinterpret_cast<const bf16x8*>(vb + (size_t)l31 * SKV_ + hi * 8);
    bf16x8 vf01 = *reinterpret_cast<const bf16x8*>(vb + (size_t)l31 * SKV_ + 16 + hi * 8);
    bf16x8 vf10 = *reinterpret_cast<const bf16x8*>(vb + (size_t)(32 + l31) * SKV_ + hi * 8);
    bf16x8 vf11 = *reinterpret_cast<const bf16x8*>(vb + (size_t)(32 + l31) * SKV_ + 16 + hi * 8);

    f32x16 s = {};
    s = __builtin_amdgcn_mfma_f32_32x32x16_bf16(kf0, qf[0], s, 0, 0, 0);
    s = __builtin_amdgcn_mfma_f32_32x32x16_bf16(kf1, qf[1], s, 0, 0, 0);
    s = __builtin_amdgcn_mfma_f32_32x32x16_bf16(kf2, qf[2], s, 0, 0, 0);
    s = __builtin_amdgcn_mfma_f32_32x32x16_bf16(kf3, qf[3], s, 0, 0, 0);

    // mask (bit=1 => -1e30) + chunk max; kv row of reg r = (r&3)+8*(r>>2)+4*hi
    float v[16];
    float cm = -1e30f;
#pragma unroll
    for (int r = 0; r < 16; ++r) {
      int bit = (r & 3) + 8 * (r >> 2) + 4 * hi;
      v[r] = ((mw >> bit) & 1u) ? -1e30f : s[r];
      cm = fmaxf(cm, v[r]);
    }
    cm = fmaxf(cm, __shfl_xor(cm, 32));         // full 32-kv row max (both half-lanes)

    // unconditional online-softmax rescale (defer-max removed this round for isolation)
    float mnew = fmaxf(mreg, cm);               // >= -1e4 floor
    float sc = __expf(mreg - mnew);
    mreg = mnew;
    lr *= sc; acc0 *= sc; acc1 *= sc;

    float p[16], rs = 0.f;
#pragma unroll
    for (int r = 0; r < 16; ++r) { p[r] = __expf(v[r] - mreg); rs += p[r]; }
    lr += rs;

    // P(f32) -> packed bf16 words; lane 'hi' holds kv {4hi+0..3, 8+4hi+0..3, 16+4hi.., 24+4hi..}
    u32 w0 = (u32)f2bf(p[0])  | ((u32)f2bf(p[1])  << 16);
    u32 w1 = (u32)f2bf(p[2])  | ((u32)f2bf(p[3])  << 16);
    u32 w2 = (u32)f2bf(p[4])  | ((u32)f2bf(p[5])  << 16);
    u32 w3 = (u32)f2bf(p[6])  | ((u32)f2bf(p[7])  << 16);
    u32 w4 = (u32)f2bf(p[8])  | ((u32)f2bf(p[9])  << 16);
    u32 w5 = (u32)f2bf(p[10]) | ((u32)f2bf(p[11]) << 16);
    u32 w6 = (u32)f2bf(p[12]) | ((u32)f2bf(p[13]) << 16);
    u32 w7 = (u32)f2bf(p[14]) | ((u32)f2bf(p[15]) << 16);
    // partner-lane copies (lane c <-> lane 32+c); same q-column both sides
    u32 x0 = __shfl_xor(w0, 32), x1 = __shfl_xor(w1, 32);
    u32 x2 = __shfl_xor(w2, 32), x3 = __shfl_xor(w3, 32);
    u32 x4 = __shfl_xor(w4, 32), x5 = __shfl_xor(w5, 32);
    u32 x6 = __shfl_xor(w6, 32), x7 = __shfl_xor(w7, 32);

    fragu f0, f1;
    // B-frag word j must hold kv {8hi+2j, 8hi+2j+1} (f0: kv0..15) / +16 (f1)
    f0.w[0] = hi ? x2 : w0;   // hi=0: {0,1}   hi=1: partner's {8,9}
    f0.w[1] = hi ? x3 : w1;   // hi=0: {2,3}   hi=1: partner's {10,11}
    f0.w[2] = hi ? w2 : x0;   // hi=0: partner's {4,5}   hi=1: own {12,13}
    f0.w[3] = hi ? w3 : x1;   // hi=0: partner's {6,7}   hi=1: own {14,15}
    f1.w[0] = hi ? x6 : w4;
    f1.w[1] = hi ? x7 : w5;
    f1.w[2] = hi ? w6 : x4;
    f1.w[3] = hi ? w7 : x5;

    acc0 = __builtin_amdgcn_mfma_f32_32x32x16_bf16(vf00, f0.f, acc0, 0, 0, 0);
    acc0 = __builtin_amdgcn_mfma_f32_32x32x16_bf16(vf01, f1.f, acc0, 0, 0, 0);
    acc1 = __builtin_amdgcn_mfma_f32_32x32x16_bf16(vf10, f0.f, acc1, 0, 0, 0);
    acc1 = __builtin_amdgcn_mfma_f32_32x32x16_bf16(vf11, f1.f, acc1, 0, 0, 0);
  }

  float lrT = lr + __shfl_xor(lr, 32);
  float inv = (lrT > 0.f) ? 1.0f / lrT : 0.f;
  float* ob = out + ((size_t)b * SQ_ + qg) * NHD_ + h * 64;
#pragma unroll
  for (int t = 0; t < 4; ++t) {   // O^T: d = 8*t + 4*hi + j (acc0: d 0..31, acc1: d 32..63)
    float4 s0 = make_float4(acc0[4 * t] * inv, acc0[4 * t + 1] * inv,
                            acc0[4 * t + 2] * inv, acc0[4 * t + 3] * inv);
    float4 s1 = make_float4(acc1[4 * t] * inv, acc1[4 * t + 1] * inv,
                            acc1[4 * t + 2] * inv, acc1[4 * t + 3] * inv);
    *reinterpret_cast<float4*>(ob + 8 * t + 4 * hi) = s0;
    *reinterpret_cast<float4*>(ob + 32 + 8 * t + 4 * hi) = s1;
  }
}

extern "C" void kernel_launch(void* const* d_in, const int* in_sizes, int n_in,
                              void* d_out, int out_size, void* d_ws, size_t ws_size,
                              hipStream_t stream) {
  const float* x_q  = (const float*)d_in[0];
  const float* x_kv = (const float*)d_in[1];
  const u32*   mask = (const u32*)d_in[2];
  const float* w_q = (const float*)d_in[3];
  const float* b_q = (const float*)d_in[4];
  const float* w_k = (const float*)d_in[5];
  const float* b_k = (const float*)d_in[6];
  const float* w_v = (const float*)d_in[7];
  const float* b_v = (const float*)d_in[8];
  float* out = (float*)d_out;

  const size_t MB = 1024 * 1024;
  char* ws = (char*)d_ws;
  u16* xq_b  = (u16*)(ws);             // 16 MB (dead after proj -> reused for Mp)
  u16* xkv_b = (u16*)(ws + 16 * MB);   // 16 MB
  u16* wt    = (u16*)(ws + 32 * MB);   //  6 MB (dead after proj -> reused for flag)
  u16* Qb    = (u16*)(ws + 38 * MB);   // 16 MB
  u16* Kb    = (u16*)(ws + 54 * MB);   // 16 MB
  u16* Vtb   = (u16*)(ws + 70 * MB);   // 16 MB  -> total 86 MB
  u32* Mp    = (u32*)(ws);             // 2 MB, overlaps xq_b (written after proj is done)
  u32* flag  = (u32*)(ws + 32 * MB);   // overlaps wt (written after proj is done)
  if (ws_size < 86 * MB) return;

  cvt_bf16_kernel<<<2048, 256, 0, stream>>>(x_q,  xq_b,  (B_ * SQ_  * E_) / 4);
  cvt_bf16_kernel<<<2048, 256, 0, stream>>>(x_kv, xkv_b, (B_ * SKV_ * E_) / 4);
  wtrans_kernel<<<dim3(32, 32, 3), 256, 0, stream>>>(w_q, w_k, w_v, wt);
  proj_kernel<<<dim3(64, 8, 3), 256, 0, stream>>>(xq_b, xkv_b, wt, b_q, b_k, b_v, Qb, Kb, Vtb);
  probe_kernel<<<1, 256, 0, stream>>>(mask, flag);
  maskpack_kernel<<<2048, 256, 0, stream>>>(mask, flag, Mp);
  attn_kernel<<<1024, 256, 0, stream>>>(Qb, Kb, Vtb, Mp, out);
}